// Round 1
// baseline (200.047 us; speedup 1.0000x reference)
//
#include <hip/hip_runtime.h>

#define NEXP 8
#define E_TOT 100000

typedef __bf16 bf16x8 __attribute__((ext_vector_type(8)));
typedef float f32x4 __attribute__((ext_vector_type(4)));
typedef unsigned short u16x8 __attribute__((ext_vector_type(8)));

union BF8 { u16x8 u; bf16x8 b; };

__device__ __forceinline__ unsigned short f2bf(float f) {
  unsigned int u = __float_as_uint(f);
  u += 0x7fffu + ((u >> 16) & 1u);           // round-to-nearest-even
  return (unsigned short)(u >> 16);
}

// XOR-swizzled element index: row r, col c, row stride (elems).
// 8-elem-aligned chunks stay contiguous (XOR only touches bits >= 3).
__device__ __forceinline__ int sidx(int r, int c, int stride) {
  return r * stride + (c ^ ((r & 7) << 3));
}

__device__ __forceinline__ void stage8(unsigned short* dst, const float* src) {
  float4 a = *(const float4*)(src);
  float4 b = *(const float4*)(src + 4);
  BF8 t;
  t.u[0]=f2bf(a.x); t.u[1]=f2bf(a.y); t.u[2]=f2bf(a.z); t.u[3]=f2bf(a.w);
  t.u[4]=f2bf(b.x); t.u[5]=f2bf(b.y); t.u[6]=f2bf(b.z); t.u[7]=f2bf(b.w);
  *(u16x8*)dst = t.u;
}

__device__ __forceinline__ bf16x8 fragld(const unsigned short* a, int off) {
  BF8 t;
  t.u = *(const u16x8*)(a + off);
  return t.b;
}

__global__ __launch_bounds__(512, 2) void k_radial(
    const float* __restrict__ xg,
    const float* __restrict__ W1c, const float* __restrict__ b1c,
    const float* __restrict__ g1p, const float* __restrict__ bt1p,
    const float* __restrict__ W2p, const float* __restrict__ b2p,
    const float* __restrict__ g2p, const float* __restrict__ bt2p,
    const float* __restrict__ W3p, const float* __restrict__ b3p,
    float* __restrict__ outp)
{
  // 128 KiB total LDS
  __shared__ __attribute__((aligned(16))) unsigned short w1s[128 * 64];   // 16 KB  B-layout: [h_out][d_in]
  __shared__ __attribute__((aligned(16))) unsigned short w2s[128 * 128];  // 32 KB  [k_out][h_in]
  __shared__ __attribute__((aligned(16))) unsigned short w3s[64 * 128];   // 16 KB  [d_out][h_in]
  __shared__ __attribute__((aligned(16))) unsigned short hs[256 * 128];   // 64 KB  activations [row][feat]

  const int n    = blockIdx.y;
  const int e0   = blockIdx.x * 256;
  const int tid  = threadIdx.x;
  const int lane = tid & 63;
  const int wv   = tid >> 6;      // wave 0..7
  const int l15  = lane & 15;
  const int gq   = lane >> 4;     // 0..3
  const int wrow = wv * 32;       // this wave's 32-row slab in the 256-row tile

  // ---- preload per-lane epilogue scalars (L2-hot, 52 VGPRs) ----
  float b1v[8], g1v[8], bt1v[8], b2v[8], g2v[8], bt2v[8], b3v[4];
#pragma unroll
  for (int ct = 0; ct < 8; ++ct) {
    int col = n * 128 + ct * 16 + l15;
    b1v[ct] = b1c[col]; g1v[ct] = g1p[col]; bt1v[ct] = bt1p[col];
    b2v[ct] = b2p[col]; g2v[ct] = g2p[col]; bt2v[ct] = bt2p[col];
  }
#pragma unroll
  for (int ct = 0; ct < 4; ++ct) b3v[ct] = b3p[n * 64 + ct * 16 + l15];

  // ---- stage this expert's weights fp32 -> bf16 into swizzled LDS ----
  {
    const float* s1 = W1c + (size_t)n * (128 * 64);
#pragma unroll
    for (int i = 0; i < 2; ++i) {
      int c = tid + i * 512;
      int r = c >> 3, ko = (c & 7) << 3;
      stage8(&w1s[sidx(r, ko, 64)], s1 + r * 64 + ko);
    }
    const float* s2 = W2p + (size_t)n * (128 * 128);
#pragma unroll
    for (int i = 0; i < 4; ++i) {
      int c = tid + i * 512;
      int r = c >> 4, ko = (c & 15) << 3;
      stage8(&w2s[sidx(r, ko, 128)], s2 + r * 128 + ko);
    }
    const float* s3 = W3p + (size_t)n * (64 * 128);
#pragma unroll
    for (int i = 0; i < 2; ++i) {
      int c = tid + i * 512;
      int r = c >> 4, ko = (c & 15) << 3;
      stage8(&w3s[sidx(r, ko, 128)], s3 + r * 128 + ko);
    }
  }

  // ---- x A-fragments straight from global (fp32 -> bf16) ----
  // A layout (16x16x32): lane holds A[row=l15][k = 8*gq + j (+32*s)]
  bf16x8 ax[2][2];
#pragma unroll
  for (int rt = 0; rt < 2; ++rt) {
    int e = e0 + wrow + rt * 16 + l15;
    if (e >= E_TOT) e = E_TOT - 1;                  // clamp; garbage rows never stored
    const float* px = xg + (size_t)e * 64 + gq * 8;
#pragma unroll
    for (int s = 0; s < 2; ++s) {
      float4 u0 = *(const float4*)(px + s * 32);
      float4 u1 = *(const float4*)(px + s * 32 + 4);
      BF8 t;
      t.u[0]=f2bf(u0.x); t.u[1]=f2bf(u0.y); t.u[2]=f2bf(u0.z); t.u[3]=f2bf(u0.w);
      t.u[4]=f2bf(u1.x); t.u[5]=f2bf(u1.y); t.u[6]=f2bf(u1.z); t.u[7]=f2bf(u1.w);
      ax[rt][s] = t.b;
    }
  }

  __syncthreads();

  f32x4 acc[2][8];
  const f32x4 zero4 = {0.f, 0.f, 0.f, 0.f};

  // LN + SiLU + bf16 store of the wave's 32x128 slab into hs.
  // D layout: col = l15 (+16*ct), row = 4*gq + j (+16*rt).
  auto ln_silu_store = [&](f32x4 (&A)[2][8], const float (&bv)[8],
                           const float (&gv)[8], const float (&btv)[8]) {
#pragma unroll
    for (int rt = 0; rt < 2; ++rt) {
      float sm[4] = {0.f,0.f,0.f,0.f}, sq[4] = {0.f,0.f,0.f,0.f};
#pragma unroll
      for (int ct = 0; ct < 8; ++ct) {
#pragma unroll
        for (int j = 0; j < 4; ++j) {
          float v = A[rt][ct][j] + bv[ct];
          A[rt][ct][j] = v;
          sm[j] += v;
          sq[j] += v * v;
        }
      }
#pragma unroll
      for (int m = 1; m <= 8; m <<= 1) {
#pragma unroll
        for (int j = 0; j < 4; ++j) {
          sm[j] += __shfl_xor(sm[j], m);
          sq[j] += __shfl_xor(sq[j], m);
        }
      }
#pragma unroll
      for (int j = 0; j < 4; ++j) {
        float mu  = sm[j] * (1.f / 128.f);
        float var = sq[j] * (1.f / 128.f) - mu * mu;
        sm[j] = mu;
        sq[j] = __builtin_amdgcn_rsqf(var + 1e-5f);
      }
      int r0 = wrow + rt * 16 + 4 * gq;
#pragma unroll
      for (int ct = 0; ct < 8; ++ct) {
#pragma unroll
        for (int j = 0; j < 4; ++j) {
          float v = (A[rt][ct][j] - sm[j]) * sq[j] * gv[ct] + btv[ct];
          // silu: v * sigmoid(v)
          v = v * __builtin_amdgcn_rcpf(1.f + __expf(-v));
          hs[sidx(r0 + j, ct * 16 + l15, 128)] = f2bf(v);
        }
      }
    }
  };

  // ---- layer 1: [32 x 64] @ [64 x 128] ----
#pragma unroll
  for (int rt = 0; rt < 2; ++rt)
#pragma unroll
    for (int ct = 0; ct < 8; ++ct) acc[rt][ct] = zero4;
#pragma unroll
  for (int s = 0; s < 2; ++s) {
#pragma unroll
    for (int ct = 0; ct < 8; ++ct) {
      bf16x8 b = fragld(w1s, sidx(ct * 16 + l15, s * 32 + gq * 8, 64));
      acc[0][ct] = __builtin_amdgcn_mfma_f32_16x16x32_bf16(ax[0][s], b, acc[0][ct], 0, 0, 0);
      acc[1][ct] = __builtin_amdgcn_mfma_f32_16x16x32_bf16(ax[1][s], b, acc[1][ct], 0, 0, 0);
    }
  }
  ln_silu_store(acc, b1v, g1v, bt1v);

  // ---- layer 2: [32 x 128] @ [128 x 128] (reads own slab only; no barrier) ----
#pragma unroll
  for (int rt = 0; rt < 2; ++rt)
#pragma unroll
    for (int ct = 0; ct < 8; ++ct) acc[rt][ct] = zero4;
#pragma unroll
  for (int ks = 0; ks < 4; ++ks) {
    bf16x8 a0 = fragld(hs, sidx(wrow + l15,      ks * 32 + gq * 8, 128));
    bf16x8 a1 = fragld(hs, sidx(wrow + 16 + l15, ks * 32 + gq * 8, 128));
#pragma unroll
    for (int ct = 0; ct < 8; ++ct) {
      bf16x8 b = fragld(w2s, sidx(ct * 16 + l15, ks * 32 + gq * 8, 128));
      acc[0][ct] = __builtin_amdgcn_mfma_f32_16x16x32_bf16(a0, b, acc[0][ct], 0, 0, 0);
      acc[1][ct] = __builtin_amdgcn_mfma_f32_16x16x32_bf16(a1, b, acc[1][ct], 0, 0, 0);
    }
  }
  ln_silu_store(acc, b2v, g2v, bt2v);

  // ---- layer 3: [32 x 128] @ [128 x 64] + b3, store ----
  f32x4 a3[2][4];
#pragma unroll
  for (int rt = 0; rt < 2; ++rt)
#pragma unroll
    for (int ct = 0; ct < 4; ++ct) a3[rt][ct] = zero4;
#pragma unroll
  for (int ks = 0; ks < 4; ++ks) {
    bf16x8 a0 = fragld(hs, sidx(wrow + l15,      ks * 32 + gq * 8, 128));
    bf16x8 a1 = fragld(hs, sidx(wrow + 16 + l15, ks * 32 + gq * 8, 128));
#pragma unroll
    for (int ct = 0; ct < 4; ++ct) {
      bf16x8 b = fragld(w3s, sidx(ct * 16 + l15, ks * 32 + gq * 8, 128));
      a3[0][ct] = __builtin_amdgcn_mfma_f32_16x16x32_bf16(a0, b, a3[0][ct], 0, 0, 0);
      a3[1][ct] = __builtin_amdgcn_mfma_f32_16x16x32_bf16(a1, b, a3[1][ct], 0, 0, 0);
    }
  }

  // out[n][e][d], fp32. Lanes 0..15 cover 16 consecutive d -> 64B segments.
#pragma unroll
  for (int rt = 0; rt < 2; ++rt) {
#pragma unroll
    for (int j = 0; j < 4; ++j) {
      int e = e0 + wrow + rt * 16 + 4 * gq + j;
      if (e < E_TOT) {
        float* po = outp + ((size_t)n * E_TOT + e) * 64 + l15;
#pragma unroll
        for (int ct = 0; ct < 4; ++ct)
          po[ct * 16] = a3[rt][ct][j] + b3v[ct];
      }
    }
  }
}

extern "C" void kernel_launch(void* const* d_in, const int* in_sizes, int n_in,
                              void* d_out, int out_size, void* d_ws, size_t ws_size,
                              hipStream_t stream) {
  (void)in_sizes; (void)n_in; (void)out_size; (void)d_ws; (void)ws_size;
  dim3 grid((E_TOT + 255) / 256, NEXP, 1);
  dim3 block(512, 1, 1);
  k_radial<<<grid, block, 0, stream>>>(
      (const float*)d_in[0], (const float*)d_in[1], (const float*)d_in[2],
      (const float*)d_in[3], (const float*)d_in[4], (const float*)d_in[5],
      (const float*)d_in[6], (const float*)d_in[7], (const float*)d_in[8],
      (const float*)d_in[9], (const float*)d_in[10], (float*)d_out);
}